// Round 9
// baseline (119.968 us; speedup 1.0000x reference)
//
#include <hip/hip_runtime.h>

// Problem constants (from reference)
#define BS 2
#define NF 16
#define CH 32
#define HW 16384      // 128*128
#define NM 8          // NUM_MASKS
#define NK 3          // NUM_CLASSES
#define MID 8         // NF/2

#define S 64          // spatial px per block
#define BPB (HW / S)  // partial rows per batch = 256
#define NBLK (BS * BPB)  // 512 blocks
#define PROW (NM * CH)   // 256 floats per partial row

// ---------------------------------------------------------------------------
// Fused kernel, round-9: R8 + IN-KERNEL FINAL REDUCTION.
//   The reduce_head dispatch (+0.5 MB ws round-trip after a full drain) is
//   replaced by a device-scope last-arrival handshake: every block stores
//   its partial row, fences, and atomically bumps a counter; blocks 0..15
//   (one per (b,m)) spin until all 512 arrived, acquire-fence, and run the
//   reduction + head in parallel. Deadlock-free under any dispatch order:
//   producers never wait, spinners (16) << resident capacity (>=256), and
//   every block increments before/without spinning.
// ---------------------------------------------------------------------------
__global__ __launch_bounds__(512, 4) void fused_kernel(
    const float* __restrict__ dec, const float* __restrict__ seg_w,
    const float* __restrict__ seg_b, const float* __restrict__ lw,
    const float* __restrict__ lb, float* __restrict__ masks_out,
    float* __restrict__ logits_out, float* __restrict__ part,
    unsigned int* __restrict__ counter) {
  __shared__ float mid[CH][S];    // 8 KB
  __shared__ float msk[NM][S];    // 2 KB
  __shared__ float pbuf[PROW];    // 1 KB
  __shared__ float red[16][CH];   // 2 KB (tail phase only)
  __shared__ float pooled[CH];

  int t = threadIdx.x;
  int bid = blockIdx.x;           // 0..511
  int b = bid >> 8;
  int chunk = bid & 255;
  int cs = chunk * S;

  int s = t & 15;                 // spatial lane (16 x float4 = 64 px)
  int c = t >> 4;                 // channel 0..31

  // --- 0. issue loads: MID first (oldest in FIFO), then f=0..15 ---
  const float* base = dec + ((size_t)(b * NF) * CH + c) * HW + cs + s * 4;
  float4 x[NF];
  x[MID] = *(const float4*)(base + (size_t)MID * CH * HW);
#pragma unroll
  for (int f = 0; f < NF; ++f)
    if (f != MID) x[f] = *(const float4*)(base + (size_t)f * CH * HW);

  // --- 1. stage mid chunk to LDS (waits only the oldest load) ---
  *(float4*)&mid[c][s * 4] = x[MID];
  __syncthreads();

  // --- 2. masks: 512 values, 1/thread; 15 pool loads still in flight ---
  {
    int m = t >> 6, px = t & 63;
    float v = seg_b[m];
#pragma unroll
    for (int cc = 0; cc < CH; ++cc) v += mid[cc][px] * seg_w[m * CH + cc];
    msk[m][px] = v;
    masks_out[(size_t)b * NM * HW + (size_t)m * HW + cs + px] = v;
  }
  __syncthreads();

  // --- 3. pool FMAs: f-outer/m-inner streams in load-retirement order ---
  float4 w[NM];
#pragma unroll
  for (int m = 0; m < NM; ++m) w[m] = *(const float4*)&msk[m][s * 4];

  float acc[NM];
#pragma unroll
  for (int m = 0; m < NM; ++m) acc[m] = 0.f;
#pragma unroll
  for (int f = 0; f < NF; ++f)
#pragma unroll
    for (int m = 0; m < NM; ++m)
      acc[m] += x[f].x * w[m].x + x[f].y * w[m].y + x[f].z * w[m].z +
                x[f].w * w[m].w;

  // --- 4. reduce across 16 spatial lanes -> LDS -> coalesced 1KB write ---
#pragma unroll
  for (int off = 8; off >= 1; off >>= 1)
#pragma unroll
    for (int m = 0; m < NM; ++m) acc[m] += __shfl_down(acc[m], off, 16);

  if (s == 0)
#pragma unroll
    for (int m = 0; m < NM; ++m) pbuf[m * CH + c] = acc[m];
  __syncthreads();
  if (t < PROW) part[(size_t)bid * PROW + t] = pbuf[t];

  // --- 5. arrival: barrier drains the part stores (vmcnt before s_barrier),
  //        then t0 release-fences and bumps the device-scope counter ---
  __syncthreads();
  if (t == 0) {
    __threadfence();  // agent-scope release: write back this XCD's L2
    __hip_atomic_fetch_add(counter, 1u, __ATOMIC_RELEASE,
                           __HIP_MEMORY_SCOPE_AGENT);
  }

  // --- 6. tail: blocks 0..15 (one per (b,m)) wait for all 512, then
  //        reduce 256 partial rows + compute the NK logits ---
  if (bid < BS * NM) {
    if (t == 0) {
      while (__hip_atomic_load(counter, __ATOMIC_ACQUIRE,
                               __HIP_MEMORY_SCOPE_AGENT) < NBLK)
        __builtin_amdgcn_s_sleep(16);
      __threadfence();  // agent-scope acquire: invalidate stale cache lines
    }
    __syncthreads();

    int rb = bid >> 3, rm = bid & 7;
    int rc = t & 31, j = t >> 5;  // j: 16-way split over 256 partials
    float sum = 0.f;
    const float* p = part + (size_t)rb * BPB * PROW + rm * CH + rc;
    for (int i = j; i < BPB; i += 16)  // 16 iterations, coalesced in rc
      sum += p[(size_t)i * PROW];
    red[j][rc] = sum;
    __syncthreads();

    if (t < CH) {
      float v = 0.f;
#pragma unroll
      for (int jj = 0; jj < 16; ++jj) v += red[jj][t];
      pooled[t] = v * (1.0f / NF);
    }
    __syncthreads();

    if (t < NK) {
      float dot = 0.f;
#pragma unroll
      for (int cc = 0; cc < CH; ++cc) dot += pooled[cc] * lw[t * CH + cc];
      logits_out[rb * (NM * NK) + rm * NK + t] = dot + lb[t];
    }
  }
}

extern "C" void kernel_launch(void* const* d_in, const int* in_sizes, int n_in,
                              void* d_out, int out_size, void* d_ws,
                              size_t ws_size, hipStream_t stream) {
  const float* dec = (const float*)d_in[0];    // (2,16,32,128,128)
  const float* seg_w = (const float*)d_in[1];  // (8,32)
  const float* seg_b = (const float*)d_in[2];  // (8,)
  const float* lw = (const float*)d_in[3];     // (3,32)
  const float* lb = (const float*)d_in[4];     // (3,)

  float* out = (float*)d_out;
  float* logits_out = out;                // 48 floats
  float* masks_out = out + BS * NM * NK;  // 262144 floats, 192 B offset
  float* part = (float*)d_ws;             // 512 x 256 floats = 0.5 MB
  unsigned int* counter = (unsigned int*)((char*)d_ws + NBLK * PROW * 4);

  hipMemsetAsync(counter, 0, sizeof(unsigned int), stream);
  fused_kernel<<<NBLK, 512, 0, stream>>>(dec, seg_w, seg_b, lw, lb, masks_out,
                                         logits_out, part, counter);
}

// Round 10
// 103.009 us; speedup vs baseline: 1.1646x; 1.1646x over previous
//
#include <hip/hip_runtime.h>

// Problem constants (from reference)
#define BS 2
#define NF 16
#define CH 32
#define HW 16384      // 128*128
#define NM 8          // NUM_MASKS
#define NK 3          // NUM_CLASSES
#define MID 8         // NF/2

#define S 64          // spatial px per block
#define BPB (HW / S)  // partial rows per batch = 256
#define NBLK (BS * BPB)  // 512 blocks

// ---------------------------------------------------------------------------
// Round-10: exact revert to the round-8 kernel (best measured: 102.5 us).
//   Round-9's in-kernel last-arrival reduction wrecked the hot loop's
//   register allocation (VGPR 64 -> x[16] alone needs 64 -> spills;
//   fused 15 -> 45 us). Lesson: the hot kernel's allocation is fragile to
//   added tail code; keep the final reduction as its own tiny dispatch.
//
// Fused kernel: one block per (b, 64-px chunk), all 16 frames.
//   - dec read exactly once (frame MID doubles as the mask staging load)
//   - mask tile computed once per pixel
//   - loads issued MID-first (vmcnt FIFO: mid LDS-write waits only the
//     oldest load; 15 pool loads stay in flight under the mask phase)
//   - pool FMAs f-outer/m-inner: stream in load-retirement order
// ---------------------------------------------------------------------------
__global__ __launch_bounds__(512, 4) void fused_kernel(
    const float* __restrict__ dec, const float* __restrict__ seg_w,
    const float* __restrict__ seg_b, float* __restrict__ masks_out,
    float* __restrict__ part) {
  __shared__ float mid[CH][S];    // 8 KB
  __shared__ float msk[NM][S];    // 2 KB
  __shared__ float pbuf[NM * CH]; // 1 KB

  int t = threadIdx.x;
  int bid = blockIdx.x;           // 0..511
  int b = bid >> 8;
  int chunk = bid & 255;
  int cs = chunk * S;

  int s = t & 15;                 // spatial lane (16 x float4 = 64 px)
  int c = t >> 4;                 // channel 0..31

  // --- 0. issue loads: MID first (oldest in FIFO), then f=0..15 ---
  const float* base = dec + ((size_t)(b * NF) * CH + c) * HW + cs + s * 4;
  float4 x[NF];
  x[MID] = *(const float4*)(base + (size_t)MID * CH * HW);
#pragma unroll
  for (int f = 0; f < NF; ++f)
    if (f != MID) x[f] = *(const float4*)(base + (size_t)f * CH * HW);

  // --- 1. stage mid chunk to LDS (waits only the oldest load) ---
  *(float4*)&mid[c][s * 4] = x[MID];
  __syncthreads();

  // --- 2. masks: 512 values, 1/thread; 15 pool loads still in flight ---
  {
    int m = t >> 6, px = t & 63;
    float v = seg_b[m];
#pragma unroll
    for (int cc = 0; cc < CH; ++cc) v += mid[cc][px] * seg_w[m * CH + cc];
    msk[m][px] = v;
    masks_out[(size_t)b * NM * HW + (size_t)m * HW + cs + px] = v;
  }
  __syncthreads();

  // --- 3. pool FMAs: f-outer/m-inner streams in load-retirement order ---
  float4 w[NM];
#pragma unroll
  for (int m = 0; m < NM; ++m) w[m] = *(const float4*)&msk[m][s * 4];

  float acc[NM];
#pragma unroll
  for (int m = 0; m < NM; ++m) acc[m] = 0.f;
#pragma unroll
  for (int f = 0; f < NF; ++f)
#pragma unroll
    for (int m = 0; m < NM; ++m)
      acc[m] += x[f].x * w[m].x + x[f].y * w[m].y + x[f].z * w[m].z +
                x[f].w * w[m].w;

  // --- 4. reduce across 16 spatial lanes -> LDS -> coalesced 1KB write ---
#pragma unroll
  for (int off = 8; off >= 1; off >>= 1)
#pragma unroll
    for (int m = 0; m < NM; ++m) acc[m] += __shfl_down(acc[m], off, 16);

  if (s == 0)
#pragma unroll
    for (int m = 0; m < NM; ++m) pbuf[m * CH + c] = acc[m];
  __syncthreads();
  if (t < NM * CH) part[(size_t)bid * (NM * CH) + t] = pbuf[t];
}

// ---------------------------------------------------------------------------
// Reduce + head: one block per (b,m), 1024 threads (32-way split over the
// 256 partial rows -> 8 strided loads/thread), then the NK-logit head.
// ---------------------------------------------------------------------------
__global__ __launch_bounds__(1024) void reduce_head_kernel(
    const float* __restrict__ part, const float* __restrict__ lw,
    const float* __restrict__ lb, float* __restrict__ out) {
  __shared__ float red[32][CH];   // 4 KB
  __shared__ float pooled[CH];

  int t = threadIdx.x;
  int b = blockIdx.x >> 3;        // 0..1
  int m = blockIdx.x & 7;         // 0..7

  int c = t & 31, j = t >> 5;     // j: 32-way split over 256 partials
  float sum = 0.f;
  const float* p = part + (size_t)b * BPB * (NM * CH) + m * CH + c;
  for (int i = j; i < BPB; i += 32)   // 8 iterations, coalesced in c
    sum += p[(size_t)i * (NM * CH)];
  red[j][c] = sum;
  __syncthreads();

  if (t < CH) {
    float v = 0.f;
#pragma unroll
    for (int jj = 0; jj < 32; ++jj) v += red[jj][t];
    pooled[t] = v * (1.0f / NF);
  }
  __syncthreads();

  if (t < NK) {
    float dot = 0.f;
#pragma unroll
    for (int cc = 0; cc < CH; ++cc) dot += pooled[cc] * lw[t * CH + cc];
    out[b * (NM * NK) + m * NK + t] = dot + lb[t];
  }
}

extern "C" void kernel_launch(void* const* d_in, const int* in_sizes, int n_in,
                              void* d_out, int out_size, void* d_ws,
                              size_t ws_size, hipStream_t stream) {
  const float* dec = (const float*)d_in[0];    // (2,16,32,128,128)
  const float* seg_w = (const float*)d_in[1];  // (8,32)
  const float* seg_b = (const float*)d_in[2];  // (8,)
  const float* lw = (const float*)d_in[3];     // (3,32)
  const float* lb = (const float*)d_in[4];     // (3,)

  float* out = (float*)d_out;
  float* logits_out = out;                // 48 floats
  float* masks_out = out + BS * NM * NK;  // 262144 floats, 192 B offset
  float* part = (float*)d_ws;             // 512 x 256 floats = 0.5 MB

  fused_kernel<<<NBLK, 512, 0, stream>>>(dec, seg_w, seg_b, masks_out, part);
  reduce_head_kernel<<<BS * NM, 1024, 0, stream>>>(part, lw, lb, logits_out);
}